// Round 2
// baseline (305.831 us; speedup 1.0000x reference)
//
#include <hip/hip_runtime.h>
#include <math.h>

#define HW 9216          // 96*96
#define WID 96
#define CIN 256
#define COUT 256
#define NTOT 18432       // B*HW
#define KC 2304          // CIN*9
#define NKS 72           // KC/32 k-steps

typedef short bf16x8 __attribute__((ext_vector_type(8)));
typedef float f32x4  __attribute__((ext_vector_type(4)));

__device__ __forceinline__ unsigned short f2bf(float f) {
    union { float f; unsigned int u; } v; v.f = f;
    unsigned int u = v.u;
    return (unsigned short)((u + 0x7fffu + ((u >> 16) & 1u)) >> 16);  // RNE
}
__device__ __forceinline__ float bflo(unsigned u) {
    union { unsigned u; float f; } v; v.u = u << 16; return v.f;
}
__device__ __forceinline__ float bfhi(unsigned u) {
    union { unsigned u; float f; } v; v.u = u & 0xFFFF0000u; return v.f;
}

// ws layout (float offsets):
//   off  : 0       .. 331776
//   stats: 331776  .. 331904
//   A'   : 331904  .. 626816   (589824 ushort, fragment-major weights)
//   xt   : 626816  .. 2986112  (bf16 NHWC: [b][p][c], 4718592 ushort)
//   B'   : 2986112 ..          (42467328 ushort, fragment-major patches)
//
// Fragment-major layout (matches 16x16x32 MFMA operand order exactly):
//   A'[(((mb*72+ks)*4 + i)*64 + lane)*8 + s] = wbf16[m=mb*64+i*16+(lane&15)][ks*32+(lane>>4)*8+s]
//   B'[(((g *72+ks)*4 + j)*64 + lane)*8 + s] = P    [n=g *64+j*16+(lane&15)][ks*32+(lane>>4)*8+s]
// => a GEMM wave reads each fragment as ONE coalesced 1KB dwordx4 (base+lane*16).

// Prologue: [0,4608) xt transpose(bf16) | [4608,5184) A' swizzle | [5184,6480) off init + stats=0
__global__ __launch_bounds__(256) void prelude(const float* __restrict__ x,
                                               unsigned short* __restrict__ xt,
                                               const float* __restrict__ cw,
                                               unsigned short* __restrict__ Aw,
                                               const float* __restrict__ offset_b,
                                               float* __restrict__ off,
                                               float* __restrict__ stats) {
    __shared__ float L[32][33];
    int blk = blockIdx.x, t = threadIdx.x;
    if (blk < 4608) {                       // x NCHW fp32 -> NHWC bf16
        int pt = blk % 288, ct = (blk / 288) & 7, b = blk / 2304;
        int pl = t & 31, ch = t >> 5;
#pragma unroll
        for (int i = 0; i < 4; i++) {
            int cl = ch * 4 + i;
            L[cl][pl] = x[((size_t)(b * CIN + ct * 32 + cl)) * HW + pt * 32 + pl];
        }
        __syncthreads();
        int cc = t & 31;
#pragma unroll
        for (int i = 0; i < 4; i++) {
            int pr = ch * 4 + i;
            xt[((size_t)(b * HW + pt * 32 + pr)) * 256 + ct * 32 + cc] = f2bf(L[cc][pr]);
        }
    } else if (blk < 5184) {                // conv_w -> A' fragment-major bf16
        int tid = (blk - 4608) * 256 + t;   // [0,147456)
        int oc = tid / 576;
        int kc = (tid % 576) * 4;           // 4 consecutive kc
        int k = kc >> 8, c = kc & 255;
        unsigned short v[4] __attribute__((aligned(8)));
#pragma unroll
        for (int i = 0; i < 4; i++)
            v[i] = f2bf(cw[((size_t)oc * 256 + c + i) * 9 + k]);
        int ks = kc >> 5, quad = (kc >> 3) & 3, sidx = kc & 7;
        int ifr = (oc >> 4) & 3, lane = quad * 16 + (oc & 15);
        size_t flat = (((size_t)((oc >> 6) * 72 + ks) * 4 + ifr) * 64 + lane) * 8 + sidx;
        *(uint2*)(Aw + flat) = *(const uint2*)v;
    } else {                                // off = bias, stats = 0
        int i = (blk - 5184) * 256 + t;
        if (i < 331776) off[i] = offset_b[(i / HW) % 18];
        if (i < 128) stats[i] = 0.f;
    }
}

// 3x3 pad-1 conv -> 18 offset channels. 16 c-chunks x 72 = 1152 blocks.
__global__ __launch_bounds__(256) void offset_conv(const float* __restrict__ x,
                                                   const float* __restrict__ ow,
                                                   float* __restrict__ off) {
    int chunk = blockIdx.x / 72;
    int pg = (blockIdx.x % 72) * 256 + threadIdx.x;
    int b  = pg / HW;
    int p  = pg % HW;
    int ho = p / WID, wo = p % WID;
    const float* xb = x + (size_t)b * CIN * HW;

    float acc[18];
#pragma unroll
    for (int ch = 0; ch < 18; ch++) acc[ch] = 0.f;

    int c0 = chunk * 16;
    for (int ci = 0; ci < 16; ci++) {
        int c = c0 + ci;
        const float* xc = xb + (size_t)c * HW;
#pragma unroll
        for (int ky = 0; ky < 3; ky++) {
            int y = ho - 1 + ky;
            if (y < 0 || y >= 96) continue;
#pragma unroll
            for (int kx = 0; kx < 3; kx++) {
                int xx = wo - 1 + kx;
                float xv = (xx >= 0 && xx < 96) ? xc[y * WID + xx] : 0.f;
                int widx = c * 9 + ky * 3 + kx;
#pragma unroll
                for (int ch = 0; ch < 18; ch++)
                    acc[ch] += xv * ow[ch * (CIN * 9) + widx];
            }
        }
    }
#pragma unroll
    for (int ch = 0; ch < 18; ch++)
        atomicAdd(&off[((size_t)b * 18 + ch) * HW + p], acc[ch]);
}

// Gather: one wave per n, 9 taps; 4 coalesced 512B bf16 corner-row reads per
// tap; scatter-stores straight into B' fragment-major layout (8B per lane).
__global__ __launch_bounds__(256) void gather4(const unsigned short* __restrict__ xt,
                                               const float* __restrict__ off,
                                               unsigned short* __restrict__ Bp) {
    int t    = threadIdx.x;
    int w    = t >> 6;
    int lane = t & 63;
    int n    = blockIdx.x * 4 + w;
    int b    = n / HW, p = n % HW;
    int ho   = p / WID, wo = p % WID;
    const unsigned short* xb = xt + (size_t)b * (HW * 256);
    const float* offb = off + (size_t)b * 18 * HW + p;
    int c4 = lane * 4;

    int jfr = (n >> 4) & 3, l15n = n & 15;
    int lhi = lane >> 3, lq = (lane >> 1) & 3, lp = lane & 1;
    size_t gbase = (size_t)(n >> 6) * 72;

#pragma unroll 3
    for (int k = 0; k < 9; k++) {
        int ky = k / 3, kx = k % 3;
        float dy = offb[(size_t)(2 * k)     * HW];
        float dx = offb[(size_t)(2 * k + 1) * HW];
        float sy = (float)(ho - 1 + ky) + dy;
        float sx = (float)(wo - 1 + kx) + dx;
        float y0f = floorf(sy), x0f = floorf(sx);
        float fy = sy - y0f, fx = sx - x0f;
        int y0 = (int)y0f, x0 = (int)x0f;
        int y1 = y0 + 1, x1 = x0 + 1;
        float vy0 = (y0 >= 0 && y0 < 96) ? 1.f : 0.f;
        float vy1 = (y1 >= 0 && y1 < 96) ? 1.f : 0.f;
        float vx0 = (x0 >= 0 && x0 < 96) ? 1.f : 0.f;
        float vx1 = (x1 >= 0 && x1 < 96) ? 1.f : 0.f;
        int iy0 = min(max(y0, 0), 95) * WID, iy1 = min(max(y1, 0), 95) * WID;
        int ix0 = min(max(x0, 0), 95),       ix1 = min(max(x1, 0), 95);
        float w0 = (1.f - fy) * (1.f - fx) * vy0 * vx0;
        float w1 = (1.f - fy) * fx         * vy0 * vx1;
        float w2 = fy         * (1.f - fx) * vy1 * vx0;
        float w3 = fy         * fx         * vy1 * vx1;

        uint2 u0 = *(const uint2*)(xb + (size_t)(iy0 + ix0) * 256 + c4);
        uint2 u1 = *(const uint2*)(xb + (size_t)(iy0 + ix1) * 256 + c4);
        uint2 u2 = *(const uint2*)(xb + (size_t)(iy1 + ix0) * 256 + c4);
        uint2 u3 = *(const uint2*)(xb + (size_t)(iy1 + ix1) * 256 + c4);
        float r0 = w0 * bflo(u0.x) + w1 * bflo(u1.x) + w2 * bflo(u2.x) + w3 * bflo(u3.x);
        float r1 = w0 * bfhi(u0.x) + w1 * bfhi(u1.x) + w2 * bfhi(u2.x) + w3 * bfhi(u3.x);
        float r2 = w0 * bflo(u0.y) + w1 * bflo(u1.y) + w2 * bflo(u2.y) + w3 * bflo(u3.y);
        float r3 = w0 * bfhi(u0.y) + w1 * bfhi(u1.y) + w2 * bfhi(u2.y) + w3 * bfhi(u3.y);
        uint2 o;
        o.x = (unsigned)f2bf(r0) | ((unsigned)f2bf(r1) << 16);
        o.y = (unsigned)f2bf(r2) | ((unsigned)f2bf(r3) << 16);
        size_t ds = (((gbase + k * 8 + lhi) * 4 + jfr) * 64 + lq * 16 + l15n) * 8 + lp * 4;
        *(uint2*)(Bp + ds) = o;
    }
}

// Split-K=4 register GEMM. Grid 1152 blocks x 256 thr (4 waves). Each wave
// computes the SAME 64Mx64N tile over 18 of the 72 k-steps (barrier-free
// main loop: fragment-major A'/B' -> 8 coalesced dwordx4 + 16 MFMA per
// k-step, ring-3 prefetch). 4x the resident waves of the old single-wave
// grid (18 waves/CU vs 4.5) to hide ~650cy L2/L3 load latency via TLP.
// Epilogue: 2-round LDS pairwise reduction (32 KB); waves 0 and 2 finalize
// half the j-tile each with fused GN stats (atomics, as before).
__global__ __launch_bounds__(256) void gemm_mfma(const unsigned short* __restrict__ Aw,
                                                 const unsigned short* __restrict__ Bp,
                                                 float* __restrict__ out,
                                                 float* __restrict__ stats) {
    __shared__ f32x4 red[2][1024];           // 2 x 16 KB
    int t    = threadIdx.x;
    int lane = t & 63;
    int kh   = t >> 6;                       // wave id = K-quarter
    int l15 = lane & 15, quad = lane >> 4;
    int f = blockIdx.x;
    int low3 = f & 7, hi = f >> 3;
    int mb = hi & 3;
    int g  = low3 + (hi >> 2) * 8;           // [0,288)

    const bf16x8* Ab = (const bf16x8*)Aw + (size_t)mb * 72 * 4 * 64 + lane;
    const bf16x8* Bb = (const bf16x8*)Bp + (size_t)g  * 72 * 4 * 64 + lane;

    f32x4 acc[4][4];
#pragma unroll
    for (int i = 0; i < 4; i++)
#pragma unroll
        for (int j = 0; j < 4; j++) acc[i][j] = (f32x4)0.f;

    bf16x8 a0[4], b0[4], a1[4], b1[4], a2[4], b2[4];

#define LOADSET(aa, bb, ks)                                   \
    {                                                         \
        _Pragma("unroll")                                     \
        for (int q = 0; q < 4; q++) {                         \
            aa[q] = Ab[((ks) * 4 + q) * 64];                  \
            bb[q] = Bb[((ks) * 4 + q) * 64];                  \
        }                                                     \
    }
#define MFMASET(aa, bb)                                                       \
    {                                                                         \
        _Pragma("unroll")                                                     \
        for (int i = 0; i < 4; i++)                                           \
            _Pragma("unroll")                                                 \
            for (int j = 0; j < 4; j++)                                       \
                acc[i][j] = __builtin_amdgcn_mfma_f32_16x16x32_bf16(          \
                    aa[i], bb[j], acc[i][j], 0, 0, 0);                        \
    }

    int ks0 = kh * 18;                       // this wave's 18 k-steps
    LOADSET(a0, b0, ks0);
    LOADSET(a1, b1, ks0 + 1);
    LOADSET(a2, b2, ks0 + 2);
    for (int kk = 0; kk < 15; kk += 3) {
        MFMASET(a0, b0); LOADSET(a0, b0, ks0 + kk + 3);
        MFMASET(a1, b1); LOADSET(a1, b1, ks0 + kk + 4);
        MFMASET(a2, b2); LOADSET(a2, b2, ks0 + kk + 5);
    }
    MFMASET(a0, b0);
    MFMASET(a1, b1);
    MFMASET(a2, b2);

    // ---- round 1: odd waves dump full acc; even waves add ----
    if (kh & 1) {
        f32x4* dst = red[kh >> 1];
#pragma unroll
        for (int i = 0; i < 4; i++)
#pragma unroll
            for (int j = 0; j < 4; j++)
                dst[lane * 16 + i * 4 + j] = acc[i][j];
    }
    __syncthreads();
    if (!(kh & 1)) {
        const f32x4* src = red[kh >> 1];
#pragma unroll
        for (int i = 0; i < 4; i++)
#pragma unroll
            for (int j = 0; j < 4; j++)
                acc[i][j] += src[lane * 16 + i * 4 + j];
    }
    __syncthreads();
    // ---- round 2: w2 dumps j{0,1} -> red[0]; w0 dumps j{2,3} -> red[1] ----
    if (kh == 2) {
#pragma unroll
        for (int i = 0; i < 4; i++)
#pragma unroll
            for (int j = 0; j < 2; j++)
                red[0][lane * 8 + i * 2 + j] = acc[i][j];
    } else if (kh == 0) {
#pragma unroll
        for (int i = 0; i < 4; i++)
#pragma unroll
            for (int j = 0; j < 2; j++)
                red[1][lane * 8 + i * 2 + j] = acc[i][j + 2];
    }
    __syncthreads();
    if ((kh & 1) == 0) {
        int j0 = (kh == 0) ? 0 : 2;
        const f32x4* src = (kh == 0) ? red[0] : red[1];
#pragma unroll
        for (int i = 0; i < 4; i++)
#pragma unroll
            for (int j = 0; j < 2; j++)
                acc[i][j0 + j] += src[lane * 8 + i * 2 + j];

        int b_ = g / 144;
        int p0 = (g % 144) * 64;
        float s[4] = {0.f, 0.f, 0.f, 0.f}, ss[4] = {0.f, 0.f, 0.f, 0.f};
#pragma unroll
        for (int i = 0; i < 4; i++) {
            int mr = mb * 64 + i * 16 + quad * 4;
#pragma unroll
            for (int j = 0; j < 2; j++) {
                float* ob = out + ((size_t)b_ * COUT + mr) * HW + p0 + (j0 + j) * 16 + l15;
#pragma unroll
                for (int r = 0; r < 4; r++) {
                    float v = acc[i][j0 + j][r];
                    ob[(size_t)r * HW] = v;
                    s[i]  += v;
                    ss[i] += v * v;
                }
            }
        }
#pragma unroll
        for (int i = 0; i < 4; i++) {
            float sv = s[i], ssv = ss[i];
#pragma unroll
            for (int d = 1; d < 32; d <<= 1) {
                sv  += __shfl_xor(sv,  d);
                ssv += __shfl_xor(ssv, d);
            }
            if ((lane & 31) == 0) {
                int bg = b_ * 32 + mb * 8 + i * 2 + (lane >> 5);
                atomicAdd(&stats[bg * 2],     sv);
                atomicAdd(&stats[bg * 2 + 1], ssv);
            }
        }
    }
}

__global__ __launch_bounds__(256) void gn_norm(float* __restrict__ out,
                                               const float* __restrict__ stats,
                                               const float* __restrict__ gamma,
                                               const float* __restrict__ beta) {
    int i4 = blockIdx.x * 256 + threadIdx.x;
    if (i4 >= 1179648) return;
    float4 v = ((const float4*)out)[i4];
    int e  = i4 * 4;
    int ch = (e / HW) & 255;
    int b  = e / (HW * 256);
    int bg = b * 32 + (ch >> 3);
    float s = stats[bg * 2], ss = stats[bg * 2 + 1];
    float mean = s * (1.f / 73728.f);
    float rs   = rsqrtf(ss * (1.f / 73728.f) - mean * mean + 1e-5f);
    float ga = gamma[ch] * rs;
    float be = beta[ch] - mean * ga;
    v.x = fmaxf(v.x * ga + be, 0.f);
    v.y = fmaxf(v.y * ga + be, 0.f);
    v.z = fmaxf(v.z * ga + be, 0.f);
    v.w = fmaxf(v.w * ga + be, 0.f);
    ((float4*)out)[i4] = v;
}

extern "C" void kernel_launch(void* const* d_in, const int* in_sizes, int n_in,
                              void* d_out, int out_size, void* d_ws, size_t ws_size,
                              hipStream_t stream) {
    const float* x        = (const float*)d_in[0];
    const float* offset_w = (const float*)d_in[1];
    const float* offset_b = (const float*)d_in[2];
    const float* conv_w   = (const float*)d_in[3];
    const float* gamma    = (const float*)d_in[4];
    const float* beta     = (const float*)d_in[5];
    float* out = (float*)d_out;
    float* ws  = (float*)d_ws;

    float*          off   = ws;
    float*          stats = ws + 331776;
    unsigned short* Aw    = (unsigned short*)(ws + 331904);
    unsigned short* xt    = (unsigned short*)(ws + 626816);
    unsigned short* Bp    = (unsigned short*)(ws + 2986112);

    hipLaunchKernelGGL(prelude,     dim3(6480), dim3(256), 0, stream,
                       x, xt, conv_w, Aw, offset_b, off, stats);
    hipLaunchKernelGGL(offset_conv, dim3(1152), dim3(256), 0, stream, x, offset_w, off);
    hipLaunchKernelGGL(gather4,     dim3(4608), dim3(256), 0, stream, xt, off, Bp);
    hipLaunchKernelGGL(gemm_mfma,   dim3(1152), dim3(256), 0, stream, Aw, Bp, out, stats);
    hipLaunchKernelGGL(gn_norm,     dim3(4608), dim3(256), 0, stream, out, stats, gamma, beta);
}

// Round 3
// 288.289 us; speedup vs baseline: 1.0608x; 1.0608x over previous
//
#include <hip/hip_runtime.h>
#include <math.h>

#define HW 9216          // 96*96
#define WID 96
#define CIN 256
#define COUT 256
#define NTOT 18432       // B*HW
#define KC 2304          // CIN*9
#define NKS 72           // KC/32 k-steps

typedef short bf16x8 __attribute__((ext_vector_type(8)));
typedef float f32x4  __attribute__((ext_vector_type(4)));

__device__ __forceinline__ unsigned short f2bf(float f) {
    union { float f; unsigned int u; } v; v.f = f;
    unsigned int u = v.u;
    return (unsigned short)((u + 0x7fffu + ((u >> 16) & 1u)) >> 16);  // RNE
}
__device__ __forceinline__ float bflo(unsigned u) {
    union { unsigned u; float f; } v; v.u = u << 16; return v.f;
}
__device__ __forceinline__ float bfhi(unsigned u) {
    union { unsigned u; float f; } v; v.u = u & 0xFFFF0000u; return v.f;
}

// ws layout (float offsets):
//   off  : 0       .. 331776
//   stats: 331776  .. 331904
//   A'   : 331904  .. 626816   (589824 ushort, fragment-major weights)
//   xt   : 626816  .. 2986112  (bf16 NHWC: [b][p][c], 4718592 ushort)
//   B'   : 2986112 ..          (42467328 ushort, fragment-major patches)
//
// Fragment-major layout (matches 16x16x32 MFMA operand order exactly):
//   A'[(((mb*72+ks)*4 + i)*64 + lane)*8 + s] = wbf16[m=mb*64+i*16+(lane&15)][ks*32+(lane>>4)*8+s]
//   B'[(((g *72+ks)*4 + j)*64 + lane)*8 + s] = P    [n=g *64+j*16+(lane&15)][ks*32+(lane>>4)*8+s]
// => a GEMM wave reads each fragment as ONE coalesced 1KB dwordx4 (base+lane*16).

// Prologue: [0,4608) xt transpose(bf16) | [4608,5184) A' swizzle | [5184,6480) off init + stats=0
__global__ __launch_bounds__(256) void prelude(const float* __restrict__ x,
                                               unsigned short* __restrict__ xt,
                                               const float* __restrict__ cw,
                                               unsigned short* __restrict__ Aw,
                                               const float* __restrict__ offset_b,
                                               float* __restrict__ off,
                                               float* __restrict__ stats) {
    __shared__ float L[32][33];
    int blk = blockIdx.x, t = threadIdx.x;
    if (blk < 4608) {                       // x NCHW fp32 -> NHWC bf16
        int pt = blk % 288, ct = (blk / 288) & 7, b = blk / 2304;
        int pl = t & 31, ch = t >> 5;
#pragma unroll
        for (int i = 0; i < 4; i++) {
            int cl = ch * 4 + i;
            L[cl][pl] = x[((size_t)(b * CIN + ct * 32 + cl)) * HW + pt * 32 + pl];
        }
        __syncthreads();
        int cc = t & 31;
#pragma unroll
        for (int i = 0; i < 4; i++) {
            int pr = ch * 4 + i;
            xt[((size_t)(b * HW + pt * 32 + pr)) * 256 + ct * 32 + cc] = f2bf(L[cc][pr]);
        }
    } else if (blk < 5184) {                // conv_w -> A' fragment-major bf16
        int tid = (blk - 4608) * 256 + t;   // [0,147456)
        int oc = tid / 576;
        int kc = (tid % 576) * 4;           // 4 consecutive kc
        int k = kc >> 8, c = kc & 255;
        unsigned short v[4] __attribute__((aligned(8)));
#pragma unroll
        for (int i = 0; i < 4; i++)
            v[i] = f2bf(cw[((size_t)oc * 256 + c + i) * 9 + k]);
        int ks = kc >> 5, quad = (kc >> 3) & 3, sidx = kc & 7;
        int ifr = (oc >> 4) & 3, lane = quad * 16 + (oc & 15);
        size_t flat = (((size_t)((oc >> 6) * 72 + ks) * 4 + ifr) * 64 + lane) * 8 + sidx;
        *(uint2*)(Aw + flat) = *(const uint2*)v;
    } else {                                // off = bias, stats = 0
        int i = (blk - 5184) * 256 + t;
        if (i < 331776) off[i] = offset_b[(i / HW) % 18];
        if (i < 128) stats[i] = 0.f;
    }
}

// 3x3 pad-1 conv -> 18 offset channels. 16 c-chunks x 72 = 1152 blocks.
__global__ __launch_bounds__(256) void offset_conv(const float* __restrict__ x,
                                                   const float* __restrict__ ow,
                                                   float* __restrict__ off) {
    int chunk = blockIdx.x / 72;
    int pg = (blockIdx.x % 72) * 256 + threadIdx.x;
    int b  = pg / HW;
    int p  = pg % HW;
    int ho = p / WID, wo = p % WID;
    const float* xb = x + (size_t)b * CIN * HW;

    float acc[18];
#pragma unroll
    for (int ch = 0; ch < 18; ch++) acc[ch] = 0.f;

    int c0 = chunk * 16;
    for (int ci = 0; ci < 16; ci++) {
        int c = c0 + ci;
        const float* xc = xb + (size_t)c * HW;
#pragma unroll
        for (int ky = 0; ky < 3; ky++) {
            int y = ho - 1 + ky;
            if (y < 0 || y >= 96) continue;
#pragma unroll
            for (int kx = 0; kx < 3; kx++) {
                int xx = wo - 1 + kx;
                float xv = (xx >= 0 && xx < 96) ? xc[y * WID + xx] : 0.f;
                int widx = c * 9 + ky * 3 + kx;
#pragma unroll
                for (int ch = 0; ch < 18; ch++)
                    acc[ch] += xv * ow[ch * (CIN * 9) + widx];
            }
        }
    }
#pragma unroll
    for (int ch = 0; ch < 18; ch++)
        atomicAdd(&off[((size_t)b * 18 + ch) * HW + p], acc[ch]);
}

// Gather: one wave per n, 9 taps; 4 coalesced 512B bf16 corner-row reads per
// tap; scatter-stores straight into B' fragment-major layout (8B per lane).
__global__ __launch_bounds__(256) void gather4(const unsigned short* __restrict__ xt,
                                               const float* __restrict__ off,
                                               unsigned short* __restrict__ Bp) {
    int t    = threadIdx.x;
    int w    = t >> 6;
    int lane = t & 63;
    int n    = blockIdx.x * 4 + w;
    int b    = n / HW, p = n % HW;
    int ho   = p / WID, wo = p % WID;
    const unsigned short* xb = xt + (size_t)b * (HW * 256);
    const float* offb = off + (size_t)b * 18 * HW + p;
    int c4 = lane * 4;

    int jfr = (n >> 4) & 3, l15n = n & 15;
    int lhi = lane >> 3, lq = (lane >> 1) & 3, lp = lane & 1;
    size_t gbase = (size_t)(n >> 6) * 72;

#pragma unroll 3
    for (int k = 0; k < 9; k++) {
        int ky = k / 3, kx = k % 3;
        float dy = offb[(size_t)(2 * k)     * HW];
        float dx = offb[(size_t)(2 * k + 1) * HW];
        float sy = (float)(ho - 1 + ky) + dy;
        float sx = (float)(wo - 1 + kx) + dx;
        float y0f = floorf(sy), x0f = floorf(sx);
        float fy = sy - y0f, fx = sx - x0f;
        int y0 = (int)y0f, x0 = (int)x0f;
        int y1 = y0 + 1, x1 = x0 + 1;
        float vy0 = (y0 >= 0 && y0 < 96) ? 1.f : 0.f;
        float vy1 = (y1 >= 0 && y1 < 96) ? 1.f : 0.f;
        float vx0 = (x0 >= 0 && x0 < 96) ? 1.f : 0.f;
        float vx1 = (x1 >= 0 && x1 < 96) ? 1.f : 0.f;
        int iy0 = min(max(y0, 0), 95) * WID, iy1 = min(max(y1, 0), 95) * WID;
        int ix0 = min(max(x0, 0), 95),       ix1 = min(max(x1, 0), 95);
        float w0 = (1.f - fy) * (1.f - fx) * vy0 * vx0;
        float w1 = (1.f - fy) * fx         * vy0 * vx1;
        float w2 = fy         * (1.f - fx) * vy1 * vx0;
        float w3 = fy         * fx         * vy1 * vx1;

        uint2 u0 = *(const uint2*)(xb + (size_t)(iy0 + ix0) * 256 + c4);
        uint2 u1 = *(const uint2*)(xb + (size_t)(iy0 + ix1) * 256 + c4);
        uint2 u2 = *(const uint2*)(xb + (size_t)(iy1 + ix0) * 256 + c4);
        uint2 u3 = *(const uint2*)(xb + (size_t)(iy1 + ix1) * 256 + c4);
        float r0 = w0 * bflo(u0.x) + w1 * bflo(u1.x) + w2 * bflo(u2.x) + w3 * bflo(u3.x);
        float r1 = w0 * bfhi(u0.x) + w1 * bfhi(u1.x) + w2 * bfhi(u2.x) + w3 * bfhi(u3.x);
        float r2 = w0 * bflo(u0.y) + w1 * bflo(u1.y) + w2 * bflo(u2.y) + w3 * bflo(u3.y);
        float r3 = w0 * bfhi(u0.y) + w1 * bfhi(u1.y) + w2 * bfhi(u2.y) + w3 * bfhi(u3.y);
        uint2 o;
        o.x = (unsigned)f2bf(r0) | ((unsigned)f2bf(r1) << 16);
        o.y = (unsigned)f2bf(r2) | ((unsigned)f2bf(r3) << 16);
        size_t ds = (((gbase + k * 8 + lhi) * 4 + jfr) * 64 + lq * 16 + l15n) * 8 + lp * 4;
        *(uint2*)(Bp + ds) = o;
    }
}

// Split-K=4 register GEMM. Grid 1152 blocks x 256 thr (4 waves). Each wave
// computes the SAME 64Mx64N tile over 18 of the 72 k-steps (barrier-free
// main loop, ring-3 prefetch). Epilogue: 2-round LDS pairwise reduction.
// Round-1 fixes vs previous attempt:
//  * ALL acc[][] indices are compile-time constants (runtime j0 had demoted
//    acc to scratch -> 200MB spill traffic; rule: runtime-indexed
//    ext_vector arrays go to local memory).
//  * LDS reduction is fragment-major red[frag*64+lane] (16B/lane contiguous
//    ds_*_b128, conflict-free; old lane-major stride-256B was 32-way).
__global__ __launch_bounds__(256) void gemm_mfma(const unsigned short* __restrict__ Aw,
                                                 const unsigned short* __restrict__ Bp,
                                                 float* __restrict__ out,
                                                 float* __restrict__ stats) {
    __shared__ f32x4 red[2][1024];           // 2 x 16 KB
    int t    = threadIdx.x;
    int lane = t & 63;
    int kh   = t >> 6;                       // wave id = K-quarter
    int l15 = lane & 15, quad = lane >> 4;
    int f = blockIdx.x;
    int low3 = f & 7, hi = f >> 3;
    int mb = hi & 3;
    int g  = low3 + (hi >> 2) * 8;           // [0,288)

    const bf16x8* Ab = (const bf16x8*)Aw + (size_t)mb * 72 * 4 * 64 + lane;
    const bf16x8* Bb = (const bf16x8*)Bp + (size_t)g  * 72 * 4 * 64 + lane;

    f32x4 acc[4][4];
#pragma unroll
    for (int i = 0; i < 4; i++)
#pragma unroll
        for (int j = 0; j < 4; j++) acc[i][j] = (f32x4)0.f;

    bf16x8 a0[4], b0[4], a1[4], b1[4], a2[4], b2[4];

#define LOADSET(aa, bb, ks)                                   \
    {                                                         \
        _Pragma("unroll")                                     \
        for (int q = 0; q < 4; q++) {                         \
            aa[q] = Ab[((ks) * 4 + q) * 64];                  \
            bb[q] = Bb[((ks) * 4 + q) * 64];                  \
        }                                                     \
    }
#define MFMASET(aa, bb)                                                       \
    {                                                                         \
        _Pragma("unroll")                                                     \
        for (int i = 0; i < 4; i++)                                           \
            _Pragma("unroll")                                                 \
            for (int j = 0; j < 4; j++)                                       \
                acc[i][j] = __builtin_amdgcn_mfma_f32_16x16x32_bf16(          \
                    aa[i], bb[j], acc[i][j], 0, 0, 0);                        \
    }

    int ks0 = kh * 18;                       // this wave's 18 k-steps
    LOADSET(a0, b0, ks0);
    LOADSET(a1, b1, ks0 + 1);
    LOADSET(a2, b2, ks0 + 2);
    for (int kk = 0; kk < 15; kk += 3) {
        MFMASET(a0, b0); LOADSET(a0, b0, ks0 + kk + 3);
        MFMASET(a1, b1); LOADSET(a1, b1, ks0 + kk + 4);
        MFMASET(a2, b2); LOADSET(a2, b2, ks0 + kk + 5);
    }
    MFMASET(a0, b0);
    MFMASET(a1, b1);
    MFMASET(a2, b2);

    // ---- round 1: odd waves dump full acc (frag-major); even waves add ----
    if (kh & 1) {
        f32x4* dst = red[kh >> 1];
#pragma unroll
        for (int i = 0; i < 4; i++)
#pragma unroll
            for (int j = 0; j < 4; j++)
                dst[(i * 4 + j) * 64 + lane] = acc[i][j];
    }
    __syncthreads();
    if (!(kh & 1)) {
        const f32x4* src = red[kh >> 1];
#pragma unroll
        for (int i = 0; i < 4; i++)
#pragma unroll
            for (int j = 0; j < 4; j++)
                acc[i][j] += src[(i * 4 + j) * 64 + lane];
    }
    __syncthreads();
    // ---- round 2: w2 dumps j{0,1} -> red[0]; w0 dumps j{2,3} -> red[1] ----
    if (kh == 2) {
#pragma unroll
        for (int i = 0; i < 4; i++)
#pragma unroll
            for (int j = 0; j < 2; j++)
                red[0][(i * 2 + j) * 64 + lane] = acc[i][j];
    } else if (kh == 0) {
#pragma unroll
        for (int i = 0; i < 4; i++)
#pragma unroll
            for (int j = 0; j < 2; j++)
                red[1][(i * 2 + j) * 64 + lane] = acc[i][j + 2];
    }
    __syncthreads();

    // ---- final: static-index accumulate + store + fused GN stats ----
#define EPILOG(RB, J0)                                                        \
    {                                                                         \
        _Pragma("unroll")                                                     \
        for (int i = 0; i < 4; i++)                                           \
            _Pragma("unroll")                                                 \
            for (int j = 0; j < 2; j++)                                       \
                acc[i][(J0) + j] += red[RB][(i * 2 + j) * 64 + lane];         \
        int b_ = g / 144;                                                     \
        int p0 = (g % 144) * 64;                                              \
        float s[4] = {0.f, 0.f, 0.f, 0.f}, ss[4] = {0.f, 0.f, 0.f, 0.f};      \
        _Pragma("unroll")                                                     \
        for (int i = 0; i < 4; i++) {                                         \
            int mr = mb * 64 + i * 16 + quad * 4;                             \
            _Pragma("unroll")                                                 \
            for (int j = 0; j < 2; j++) {                                     \
                float* ob = out + ((size_t)b_ * COUT + mr) * HW + p0          \
                            + ((J0) + j) * 16 + l15;                          \
                _Pragma("unroll")                                             \
                for (int r = 0; r < 4; r++) {                                 \
                    float v = acc[i][(J0) + j][r];                            \
                    ob[(size_t)r * HW] = v;                                   \
                    s[i]  += v;                                               \
                    ss[i] += v * v;                                           \
                }                                                             \
            }                                                                 \
        }                                                                     \
        _Pragma("unroll")                                                     \
        for (int i = 0; i < 4; i++) {                                         \
            float sv = s[i], ssv = ss[i];                                     \
            _Pragma("unroll")                                                 \
            for (int d = 1; d < 32; d <<= 1) {                                \
                sv  += __shfl_xor(sv,  d);                                    \
                ssv += __shfl_xor(ssv, d);                                    \
            }                                                                 \
            if ((lane & 31) == 0) {                                           \
                int bg = b_ * 32 + mb * 8 + i * 2 + (lane >> 5);              \
                atomicAdd(&stats[bg * 2],     sv);                            \
                atomicAdd(&stats[bg * 2 + 1], ssv);                           \
            }                                                                 \
        }                                                                     \
    }

    if (kh == 0) {
        EPILOG(0, 0);
    } else if (kh == 2) {
        EPILOG(1, 2);
    }
}

__global__ __launch_bounds__(256) void gn_norm(float* __restrict__ out,
                                               const float* __restrict__ stats,
                                               const float* __restrict__ gamma,
                                               const float* __restrict__ beta) {
    int i4 = blockIdx.x * 256 + threadIdx.x;
    if (i4 >= 1179648) return;
    float4 v = ((const float4*)out)[i4];
    int e  = i4 * 4;
    int ch = (e / HW) & 255;
    int b  = e / (HW * 256);
    int bg = b * 32 + (ch >> 3);
    float s = stats[bg * 2], ss = stats[bg * 2 + 1];
    float mean = s * (1.f / 73728.f);
    float rs   = rsqrtf(ss * (1.f / 73728.f) - mean * mean + 1e-5f);
    float ga = gamma[ch] * rs;
    float be = beta[ch] - mean * ga;
    v.x = fmaxf(v.x * ga + be, 0.f);
    v.y = fmaxf(v.y * ga + be, 0.f);
    v.z = fmaxf(v.z * ga + be, 0.f);
    v.w = fmaxf(v.w * ga + be, 0.f);
    ((float4*)out)[i4] = v;
}

extern "C" void kernel_launch(void* const* d_in, const int* in_sizes, int n_in,
                              void* d_out, int out_size, void* d_ws, size_t ws_size,
                              hipStream_t stream) {
    const float* x        = (const float*)d_in[0];
    const float* offset_w = (const float*)d_in[1];
    const float* offset_b = (const float*)d_in[2];
    const float* conv_w   = (const float*)d_in[3];
    const float* gamma    = (const float*)d_in[4];
    const float* beta     = (const float*)d_in[5];
    float* out = (float*)d_out;
    float* ws  = (float*)d_ws;

    float*          off   = ws;
    float*          stats = ws + 331776;
    unsigned short* Aw    = (unsigned short*)(ws + 331904);
    unsigned short* xt    = (unsigned short*)(ws + 626816);
    unsigned short* Bp    = (unsigned short*)(ws + 2986112);

    hipLaunchKernelGGL(prelude,     dim3(6480), dim3(256), 0, stream,
                       x, xt, conv_w, Aw, offset_b, off, stats);
    hipLaunchKernelGGL(offset_conv, dim3(1152), dim3(256), 0, stream, x, offset_w, off);
    hipLaunchKernelGGL(gather4,     dim3(4608), dim3(256), 0, stream, xt, off, Bp);
    hipLaunchKernelGGL(gemm_mfma,   dim3(1152), dim3(256), 0, stream, Aw, Bp, out, stats);
    hipLaunchKernelGGL(gn_norm,     dim3(4608), dim3(256), 0, stream, out, stats, gamma, beta);
}

// Round 4
// 259.417 us; speedup vs baseline: 1.1789x; 1.1113x over previous
//
#include <hip/hip_runtime.h>
#include <math.h>

#define HW 9216          // 96*96
#define WID 96
#define CIN 256
#define COUT 256
#define NTOT 18432       // B*HW
#define KC 2304          // CIN*9
#define NKS 72           // KC/32 k-steps

typedef short bf16x8 __attribute__((ext_vector_type(8)));
typedef float f32x4  __attribute__((ext_vector_type(4)));

__device__ __forceinline__ unsigned short f2bf(float f) {
    union { float f; unsigned int u; } v; v.f = f;
    unsigned int u = v.u;
    return (unsigned short)((u + 0x7fffu + ((u >> 16) & 1u)) >> 16);  // RNE
}
__device__ __forceinline__ float bflo(unsigned u) {
    union { unsigned u; float f; } v; v.u = u << 16; return v.f;
}
__device__ __forceinline__ float bfhi(unsigned u) {
    union { unsigned u; float f; } v; v.u = u & 0xFFFF0000u; return v.f;
}

__device__ __forceinline__ void gload_lds16(const void* g, void* l) {
    __builtin_amdgcn_global_load_lds(
        (const __attribute__((address_space(1))) unsigned int*)g,
        (__attribute__((address_space(3))) unsigned int*)l,
        16, 0, 0);
}

// ws layout (float offsets):
//   off  : 0       .. 331776
//   stats: 331776  .. 331904
//   A'   : 331904  .. 626816   (589824 ushort, fragment-major weights)
//   xt   : 626816  .. 2986112  (bf16 NHWC: [b][p][c], 4718592 ushort)
//   B'   : 2986112 ..          (42467328 ushort, fragment-major patches)
//
// Fragment-major layout (matches 16x16x32 MFMA operand order exactly):
//   A'[(((mb*72+ks)*4 + i)*64 + lane)*8 + s] = wbf16[m=mb*64+i*16+(lane&15)][ks*32+(lane>>4)*8+s]
//   B'[(((g *72+ks)*4 + j)*64 + lane)*8 + s] = P    [n=g *64+j*16+(lane&15)][ks*32+(lane>>4)*8+s]
// => one k-step of B' for a g-tile is a CONTIGUOUS 4 KB run (ideal for
//    global_load_lds staging), and a GEMM wave reads each fragment as one
//    coalesced 1KB dwordx4 (base+lane*16).

// Prologue: [0,4608) xt transpose(bf16) | [4608,5184) A' swizzle | [5184,6480) off init + stats=0
__global__ __launch_bounds__(256) void prelude(const float* __restrict__ x,
                                               unsigned short* __restrict__ xt,
                                               const float* __restrict__ cw,
                                               unsigned short* __restrict__ Aw,
                                               const float* __restrict__ offset_b,
                                               float* __restrict__ off,
                                               float* __restrict__ stats) {
    __shared__ float L[32][33];
    int blk = blockIdx.x, t = threadIdx.x;
    if (blk < 4608) {                       // x NCHW fp32 -> NHWC bf16
        int pt = blk % 288, ct = (blk / 288) & 7, b = blk / 2304;
        int pl = t & 31, ch = t >> 5;
#pragma unroll
        for (int i = 0; i < 4; i++) {
            int cl = ch * 4 + i;
            L[cl][pl] = x[((size_t)(b * CIN + ct * 32 + cl)) * HW + pt * 32 + pl];
        }
        __syncthreads();
        int cc = t & 31;
#pragma unroll
        for (int i = 0; i < 4; i++) {
            int pr = ch * 4 + i;
            xt[((size_t)(b * HW + pt * 32 + pr)) * 256 + ct * 32 + cc] = f2bf(L[cc][pr]);
        }
    } else if (blk < 5184) {                // conv_w -> A' fragment-major bf16
        int tid = (blk - 4608) * 256 + t;   // [0,147456)
        int oc = tid / 576;
        int kc = (tid % 576) * 4;           // 4 consecutive kc
        int k = kc >> 8, c = kc & 255;
        unsigned short v[4] __attribute__((aligned(8)));
#pragma unroll
        for (int i = 0; i < 4; i++)
            v[i] = f2bf(cw[((size_t)oc * 256 + c + i) * 9 + k]);
        int ks = kc >> 5, quad = (kc >> 3) & 3, sidx = kc & 7;
        int ifr = (oc >> 4) & 3, lane = quad * 16 + (oc & 15);
        size_t flat = (((size_t)((oc >> 6) * 72 + ks) * 4 + ifr) * 64 + lane) * 8 + sidx;
        *(uint2*)(Aw + flat) = *(const uint2*)v;
    } else {                                // off = bias, stats = 0
        int i = (blk - 5184) * 256 + t;
        if (i < 331776) off[i] = offset_b[(i / HW) % 18];
        if (i < 128) stats[i] = 0.f;
    }
}

// 3x3 pad-1 conv -> 18 offset channels. 16 c-chunks x 72 = 1152 blocks.
__global__ __launch_bounds__(256) void offset_conv(const float* __restrict__ x,
                                                   const float* __restrict__ ow,
                                                   float* __restrict__ off) {
    int chunk = blockIdx.x / 72;
    int pg = (blockIdx.x % 72) * 256 + threadIdx.x;
    int b  = pg / HW;
    int p  = pg % HW;
    int ho = p / WID, wo = p % WID;
    const float* xb = x + (size_t)b * CIN * HW;

    float acc[18];
#pragma unroll
    for (int ch = 0; ch < 18; ch++) acc[ch] = 0.f;

    int c0 = chunk * 16;
    for (int ci = 0; ci < 16; ci++) {
        int c = c0 + ci;
        const float* xc = xb + (size_t)c * HW;
#pragma unroll
        for (int ky = 0; ky < 3; ky++) {
            int y = ho - 1 + ky;
            if (y < 0 || y >= 96) continue;
#pragma unroll
            for (int kx = 0; kx < 3; kx++) {
                int xx = wo - 1 + kx;
                float xv = (xx >= 0 && xx < 96) ? xc[y * WID + xx] : 0.f;
                int widx = c * 9 + ky * 3 + kx;
#pragma unroll
                for (int ch = 0; ch < 18; ch++)
                    acc[ch] += xv * ow[ch * (CIN * 9) + widx];
            }
        }
    }
#pragma unroll
    for (int ch = 0; ch < 18; ch++)
        atomicAdd(&off[((size_t)b * 18 + ch) * HW + p], acc[ch]);
}

// Gather: one wave per n, 9 taps; 4 coalesced 512B bf16 corner-row reads per
// tap; scatter-stores straight into B' fragment-major layout (8B per lane).
__global__ __launch_bounds__(256) void gather4(const unsigned short* __restrict__ xt,
                                               const float* __restrict__ off,
                                               unsigned short* __restrict__ Bp) {
    int t    = threadIdx.x;
    int w    = t >> 6;
    int lane = t & 63;
    int n    = blockIdx.x * 4 + w;
    int b    = n / HW, p = n % HW;
    int ho   = p / WID, wo = p % WID;
    const unsigned short* xb = xt + (size_t)b * (HW * 256);
    const float* offb = off + (size_t)b * 18 * HW + p;
    int c4 = lane * 4;

    int jfr = (n >> 4) & 3, l15n = n & 15;
    int lhi = lane >> 3, lq = (lane >> 1) & 3, lp = lane & 1;
    size_t gbase = (size_t)(n >> 6) * 72;

#pragma unroll 3
    for (int k = 0; k < 9; k++) {
        int ky = k / 3, kx = k % 3;
        float dy = offb[(size_t)(2 * k)     * HW];
        float dx = offb[(size_t)(2 * k + 1) * HW];
        float sy = (float)(ho - 1 + ky) + dy;
        float sx = (float)(wo - 1 + kx) + dx;
        float y0f = floorf(sy), x0f = floorf(sx);
        float fy = sy - y0f, fx = sx - x0f;
        int y0 = (int)y0f, x0 = (int)x0f;
        int y1 = y0 + 1, x1 = x0 + 1;
        float vy0 = (y0 >= 0 && y0 < 96) ? 1.f : 0.f;
        float vy1 = (y1 >= 0 && y1 < 96) ? 1.f : 0.f;
        float vx0 = (x0 >= 0 && x0 < 96) ? 1.f : 0.f;
        float vx1 = (x1 >= 0 && x1 < 96) ? 1.f : 0.f;
        int iy0 = min(max(y0, 0), 95) * WID, iy1 = min(max(y1, 0), 95) * WID;
        int ix0 = min(max(x0, 0), 95),       ix1 = min(max(x1, 0), 95);
        float w0 = (1.f - fy) * (1.f - fx) * vy0 * vx0;
        float w1 = (1.f - fy) * fx         * vy0 * vx1;
        float w2 = fy         * (1.f - fx) * vy1 * vx0;
        float w3 = fy         * fx         * vy1 * vx1;

        uint2 u0 = *(const uint2*)(xb + (size_t)(iy0 + ix0) * 256 + c4);
        uint2 u1 = *(const uint2*)(xb + (size_t)(iy0 + ix1) * 256 + c4);
        uint2 u2 = *(const uint2*)(xb + (size_t)(iy1 + ix0) * 256 + c4);
        uint2 u3 = *(const uint2*)(xb + (size_t)(iy1 + ix1) * 256 + c4);
        float r0 = w0 * bflo(u0.x) + w1 * bflo(u1.x) + w2 * bflo(u2.x) + w3 * bflo(u3.x);
        float r1 = w0 * bfhi(u0.x) + w1 * bfhi(u1.x) + w2 * bfhi(u2.x) + w3 * bfhi(u3.x);
        float r2 = w0 * bflo(u0.y) + w1 * bflo(u1.y) + w2 * bflo(u2.y) + w3 * bflo(u3.y);
        float r3 = w0 * bfhi(u0.y) + w1 * bfhi(u1.y) + w2 * bfhi(u2.y) + w3 * bfhi(u3.y);
        uint2 o;
        o.x = (unsigned)f2bf(r0) | ((unsigned)f2bf(r1) << 16);
        o.y = (unsigned)f2bf(r2) | ((unsigned)f2bf(r3) << 16);
        size_t ds = (((gbase + k * 8 + lhi) * 4 + jfr) * 64 + lq * 16 + l15n) * 8 + lp * 4;
        *(uint2*)(Bp + ds) = o;
    }
}

// L2-traffic-reduced GEMM. Grid 288 blocks x 256 thr; block = one 64-col
// g-tile x FULL M=256 (wave w computes rows [w*64, w*64+64)). The binding
// resource (r1/r3 counters + model) is per-CU L2 delivery (~64 B/cy): at
// 4.5 waves/CU the old per-wave 8KB/k-step demanded ~116 B/cy. Here B' is
// staged ONCE per block into LDS via global_load_lds (chunk = 9 k-steps =
// 36 KB, double-buffered = 72 KB) and reused by all 4 waves; A' stays a
// per-wave register ring (ring-3, L2-hit stream). Per-wave L2 demand drops
// to ~5 KB/k-step -> predicted duty ~86% vs measured 54%.
__global__ __launch_bounds__(256) void gemm_mfma(const unsigned short* __restrict__ Aw,
                                                 const unsigned short* __restrict__ Bp,
                                                 float* __restrict__ out,
                                                 float* __restrict__ stats) {
    __shared__ bf16x8 Bs[2][9 * 4 * 64];     // 2 x 36 KB
    int t    = threadIdx.x;
    int lane = t & 63;
    int kh   = t >> 6;                       // wave id = mb (M-block)
    int l15 = lane & 15, quad = lane >> 4;
    int g = blockIdx.x;                      // [0,288)

    const bf16x8* Ab = (const bf16x8*)Aw + (size_t)kh * 72 * 4 * 64 + lane;
    const char*   gB = (const char*)Bp + (size_t)g * 294912;   // 72 ks * 4 KB

    f32x4 acc[4][4];
#pragma unroll
    for (int i = 0; i < 4; i++)
#pragma unroll
        for (int j = 0; j < 4; j++) acc[i][j] = (f32x4)0.f;

    bf16x8 a0[4], a1[4], a2[4];

#define LOADA(aa, ks)                                         \
    {                                                         \
        _Pragma("unroll")                                     \
        for (int q = 0; q < 4; q++)                           \
            aa[q] = Ab[((ks) * 4 + q) * 64];                  \
    }
    // 36 KB chunk stage: 9 rounds x (256 thr x 16 B). Within a wave the LDS
    // dest is wave-uniform base + lane*16 (global_load_lds HW requirement).
#define STAGE(c_, buf_)                                                       \
    {                                                                         \
        const char* s_ = gB + (size_t)(c_) * 36864 + t * 16;                  \
        char*       d_ = (char*)&Bs[buf_][0] + t * 16;                        \
        _Pragma("unroll")                                                     \
        for (int r = 0; r < 9; r++)                                           \
            gload_lds16(s_ + r * 4096, d_ + r * 4096);                        \
    }
    // one k-step: 4 x ds_read_b128 (B frags, shared) + 16 MFMA + A prefetch
#define STEP(aa, ksl, ks, DO_LOAD)                                            \
    {                                                                         \
        bf16x8 bb[4];                                                         \
        _Pragma("unroll")                                                     \
        for (int q = 0; q < 4; q++) bb[q] = bcur[((ksl) * 4 + q) * 64 + lane];\
        _Pragma("unroll")                                                     \
        for (int i = 0; i < 4; i++)                                           \
            _Pragma("unroll")                                                 \
            for (int j = 0; j < 4; j++)                                       \
                acc[i][j] = __builtin_amdgcn_mfma_f32_16x16x32_bf16(          \
                    aa[i], bb[j], acc[i][j], 0, 0, 0);                        \
        if (DO_LOAD) LOADA(aa, (ks) + 3);                                     \
    }

    STAGE(0, 0);
    LOADA(a0, 0);
    LOADA(a1, 1);
    LOADA(a2, 2);
    __syncthreads();                          // stage(0) complete (vmcnt drain)

    for (int c = 0; c < 8; c++) {
        if (c < 7) STAGE(c + 1, (c + 1) & 1);
        const bf16x8* bcur = Bs[c & 1];
        int base = c * 9;
#pragma unroll
        for (int kt = 0; kt < 3; kt++) {
            STEP(a0, kt * 3 + 0, base + kt * 3 + 0, true);
            STEP(a1, kt * 3 + 1, base + kt * 3 + 1, true);
            STEP(a2, kt * 3 + 2, base + kt * 3 + 2, (c < 7) || (kt < 2));
        }
        __syncthreads();                      // readers done + next stage landed
    }

    // ---- epilogue: store + fused GN partial stats (wave kh = mb) ----
    int b_ = g / 144;
    int p0 = (g % 144) * 64;
    float s[4] = {0.f, 0.f, 0.f, 0.f}, ss[4] = {0.f, 0.f, 0.f, 0.f};
#pragma unroll
    for (int i = 0; i < 4; i++) {
        int mr = kh * 64 + i * 16 + quad * 4;
#pragma unroll
        for (int j = 0; j < 4; j++) {
            float* ob = out + ((size_t)b_ * COUT + mr) * HW + p0 + j * 16 + l15;
#pragma unroll
            for (int r = 0; r < 4; r++) {
                float v = acc[i][j][r];
                ob[(size_t)r * HW] = v;
                s[i]  += v;
                ss[i] += v * v;
            }
        }
    }
#pragma unroll
    for (int i = 0; i < 4; i++) {
        float sv = s[i], ssv = ss[i];
#pragma unroll
        for (int d = 1; d < 32; d <<= 1) {
            sv  += __shfl_xor(sv,  d);
            ssv += __shfl_xor(ssv, d);
        }
        if ((lane & 31) == 0) {
            int bg = b_ * 32 + kh * 8 + i * 2 + (lane >> 5);
            atomicAdd(&stats[bg * 2],     sv);
            atomicAdd(&stats[bg * 2 + 1], ssv);
        }
    }
}

__global__ __launch_bounds__(256) void gn_norm(float* __restrict__ out,
                                               const float* __restrict__ stats,
                                               const float* __restrict__ gamma,
                                               const float* __restrict__ beta) {
    int i4 = blockIdx.x * 256 + threadIdx.x;
    if (i4 >= 1179648) return;
    float4 v = ((const float4*)out)[i4];
    int e  = i4 * 4;
    int ch = (e / HW) & 255;
    int b  = e / (HW * 256);
    int bg = b * 32 + (ch >> 3);
    float s = stats[bg * 2], ss = stats[bg * 2 + 1];
    float mean = s * (1.f / 73728.f);
    float rs   = rsqrtf(ss * (1.f / 73728.f) - mean * mean + 1e-5f);
    float ga = gamma[ch] * rs;
    float be = beta[ch] - mean * ga;
    v.x = fmaxf(v.x * ga + be, 0.f);
    v.y = fmaxf(v.y * ga + be, 0.f);
    v.z = fmaxf(v.z * ga + be, 0.f);
    v.w = fmaxf(v.w * ga + be, 0.f);
    ((float4*)out)[i4] = v;
}

extern "C" void kernel_launch(void* const* d_in, const int* in_sizes, int n_in,
                              void* d_out, int out_size, void* d_ws, size_t ws_size,
                              hipStream_t stream) {
    const float* x        = (const float*)d_in[0];
    const float* offset_w = (const float*)d_in[1];
    const float* offset_b = (const float*)d_in[2];
    const float* conv_w   = (const float*)d_in[3];
    const float* gamma    = (const float*)d_in[4];
    const float* beta     = (const float*)d_in[5];
    float* out = (float*)d_out;
    float* ws  = (float*)d_ws;

    float*          off   = ws;
    float*          stats = ws + 331776;
    unsigned short* Aw    = (unsigned short*)(ws + 331904);
    unsigned short* xt    = (unsigned short*)(ws + 626816);
    unsigned short* Bp    = (unsigned short*)(ws + 2986112);

    hipLaunchKernelGGL(prelude,     dim3(6480), dim3(256), 0, stream,
                       x, xt, conv_w, Aw, offset_b, off, stats);
    hipLaunchKernelGGL(offset_conv, dim3(1152), dim3(256), 0, stream, x, offset_w, off);
    hipLaunchKernelGGL(gather4,     dim3(4608), dim3(256), 0, stream, xt, off, Bp);
    hipLaunchKernelGGL(gemm_mfma,   dim3(288),  dim3(256), 0, stream, Aw, Bp, out, stats);
    hipLaunchKernelGGL(gn_norm,     dim3(4608), dim3(256), 0, stream, out, stats, gamma, beta);
}